// Round 1
// baseline (443.444 us; speedup 1.0000x reference)
//
#include <hip/hip_runtime.h>
#include <math.h>

#define LAG 168
#define HOR 24
#define DM 6
#define FFD 18
#define NL 3
#define BLK 192
#define LNEPS 1e-5f

__device__ __forceinline__ void ln6(const float* r, const float* g, const float* bb, float* outv) {
    float m = (r[0] + r[1] + r[2] + r[3] + r[4] + r[5]) * (1.0f / 6.0f);
    float v = 0.f;
#pragma unroll
    for (int d = 0; d < DM; ++d) { float t = r[d] - m; v += t * t; }
    v *= (1.0f / 6.0f);
    float rs = rsqrtf(v + LNEPS);
#pragma unroll
    for (int d = 0; d < DM; ++d) outv[d] = (r[d] - m) * rs * g[d] + bb[d];
}

__global__ __launch_bounds__(BLK) void tfenc_kernel(
    const float* __restrict__ input, const float* __restrict__ pos_emb,
    const float* __restrict__ ipw, const float* __restrict__ ipb,
    const float* __restrict__ ow,  const float* __restrict__ ob,
    const float* __restrict__ l1g, const float* __restrict__ l1b,
    const float* __restrict__ f1w, const float* __restrict__ f1b,
    const float* __restrict__ f2w, const float* __restrict__ f2b,
    const float* __restrict__ l2g, const float* __restrict__ l2b,
    const float* __restrict__ hw,  const float* __restrict__ hb,
    float* __restrict__ out)
{
    __shared__ float K[LAG][8];
    __shared__ float V[LAG][8];
    __shared__ float red[8][25];

    const int b = blockIdx.x;
    const int tid = threadIdx.x;
    const int l = tid;
    const bool act = (l < LAG);

    float hv[DM], xv[DM];
    if (act) {
        xv[0] = input[(size_t)b * LAG + l];
#pragma unroll
        for (int j = 0; j < 5; ++j) xv[1 + j] = pos_emb[l * 5 + j];
#pragma unroll
        for (int d = 0; d < DM; ++d) hv[d] = xv[d];
    }

    const float scale = 0.4082482904638631f;  // 1/sqrt(6)

    for (int i = 0; i < NL; ++i) {
        const float* Wip = ipw + i * 3 * DM * DM;
        const float* bip = ipb + i * 3 * DM;

        if (i > 0) __syncthreads();   // prev layer's attention done reading K,V

        float q[DM];
        if (act) {
#pragma unroll
            for (int e = 0; e < 3 * DM; ++e) {
                float a = bip[e];
#pragma unroll
                for (int d = 0; d < DM; ++d) a += hv[d] * Wip[e * DM + d];
                if (e < DM)            q[e] = a * scale;
                else if (e < 2 * DM)   K[l][e - DM] = a;
                else                   V[l][e - 2 * DM] = a;
            }
        }
        __syncthreads();              // K,V visible

        if (act) {
            // ---- attention (online, no max-subtract: |scores| << 80) ----
            float s = 0.f;
            float acc[DM] = {0.f, 0.f, 0.f, 0.f, 0.f, 0.f};
#pragma unroll 4
            for (int j = 0; j < LAG; ++j) {
                float4 k4 = *(const float4*)&K[j][0];
                float2 k2 = *(const float2*)&K[j][4];
                float sc = q[0] * k4.x + q[1] * k4.y + q[2] * k4.z
                         + q[3] * k4.w + q[4] * k2.x + q[5] * k2.y;
                float w = __expf(sc);
                s += w;
                float4 v4 = *(const float4*)&V[j][0];
                float2 v2 = *(const float2*)&V[j][4];
                acc[0] += w * v4.x; acc[1] += w * v4.y; acc[2] += w * v4.z;
                acc[3] += w * v4.w; acc[4] += w * v2.x; acc[5] += w * v2.y;
            }
            float inv = 1.0f / s;
            float o[DM];
#pragma unroll
            for (int d = 0; d < DM; ++d) o[d] = acc[d] * inv;

            // ---- output projection + residual ----
            const float* Wo = ow + i * DM * DM;
            const float* bo = ob + i * DM;
            float r[DM];
#pragma unroll
            for (int e = 0; e < DM; ++e) {
                float a = bo[e];
#pragma unroll
                for (int d = 0; d < DM; ++d) a += o[d] * Wo[e * DM + d];
                r[e] = hv[e] + a;
            }
            ln6(r, l1g + i * DM, l1b + i * DM, hv);

            // ---- feedforward (streamed, no f[18] array) ----
            const float* W1 = f1w + i * FFD * DM;
            const float* b1 = f1b + i * FFD;
            const float* W2 = f2w + i * DM * FFD;
            const float* b2 = f2b + i * DM;
            float o2[DM];
#pragma unroll
            for (int d = 0; d < DM; ++d) o2[d] = b2[d];
#pragma unroll
            for (int ff = 0; ff < FFD; ++ff) {
                float a = b1[ff];
#pragma unroll
                for (int d = 0; d < DM; ++d) a += hv[d] * W1[ff * DM + d];
                a = fmaxf(a, 0.f);
#pragma unroll
                for (int d = 0; d < DM; ++d) o2[d] += a * W2[d * FFD + ff];
            }
#pragma unroll
            for (int d = 0; d < DM; ++d) r[d] = hv[d] + o2[d];
            ln6(r, l2g + i * DM, l2b + i * DM, hv);
        }
    }

    // ---- final residual + relu, flatten into LDS (reuse K buffer) ----
    __syncthreads();                  // last layer's attention done with K
    float* hf = &K[0][0];
    if (act) {
#pragma unroll
        for (int d = 0; d < DM; ++d) hf[l * DM + d] = fmaxf(hv[d] + xv[d], 0.f);
    }
    __syncthreads();

    // ---- head: out[b][t] = hf . head_w[t] + head_b[t]; 24 x 8 split ----
    {
        const int t = tid % HOR;      // 0..23
        const int c = tid / HOR;      // 0..7
        const float* wrow = hw + (size_t)t * (LAG * DM) + c * 126;
        const float* hrow = hf + c * 126;
        float p = 0.f;
#pragma unroll 7
        for (int k = 0; k < 63; ++k) {
            float2 w2 = *(const float2*)&wrow[k * 2];
            p += w2.x * hrow[k * 2] + w2.y * hrow[k * 2 + 1];
        }
        red[c][t] = p;
    }
    __syncthreads();
    if (tid < HOR) {
        float p = hb[tid];
#pragma unroll
        for (int c = 0; c < 8; ++c) p += red[c][tid];
        out[(size_t)b * HOR + tid] = p;
    }
}

extern "C" void kernel_launch(void* const* d_in, const int* in_sizes, int n_in,
                              void* d_out, int out_size, void* d_ws, size_t ws_size,
                              hipStream_t stream) {
    const float* input   = (const float*)d_in[0];
    const float* pos_emb = (const float*)d_in[1];
    const float* ipw     = (const float*)d_in[2];
    const float* ipb     = (const float*)d_in[3];
    const float* ow      = (const float*)d_in[4];
    const float* ob      = (const float*)d_in[5];
    const float* l1g     = (const float*)d_in[6];
    const float* l1b     = (const float*)d_in[7];
    const float* f1w     = (const float*)d_in[8];
    const float* f1b     = (const float*)d_in[9];
    const float* f2w     = (const float*)d_in[10];
    const float* f2b     = (const float*)d_in[11];
    const float* l2g     = (const float*)d_in[12];
    const float* l2b     = (const float*)d_in[13];
    const float* hw      = (const float*)d_in[14];
    const float* hb      = (const float*)d_in[15];
    float* out = (float*)d_out;

    const int B = in_sizes[0] / LAG;
    tfenc_kernel<<<dim3(B), dim3(BLK), 0, stream>>>(
        input, pos_emb, ipw, ipb, ow, ob, l1g, l1b,
        f1w, f1b, f2w, f2b, l2g, l2b, hw, hb, out);
}

// Round 2
// 186.123 us; speedup vs baseline: 2.3825x; 2.3825x over previous
//
#include <hip/hip_runtime.h>
#include <math.h>

#define LAG 168
#define HOR 24
#define DM 6
#define FFD 18
#define NL 3
#define LNEPS 1e-5f

typedef unsigned int u32;
typedef float f32x4 __attribute__((ext_vector_type(4)));
typedef float f32x16 __attribute__((ext_vector_type(16)));
typedef short s16x8 __attribute__((ext_vector_type(8)));
typedef __bf16 bfx2 __attribute__((ext_vector_type(2)));

// LDS layout (in 4-byte words)
#define VT    0      // V^T: 8 rows x 100 words (bf16 [8][200]); row6=ones, row7=zeros
#define PP    800    // P-pack: 2 buffers x 576 words (32 q x 18 pitch)
#define OO    1952   // O: 192 q x 7 words
#define HEADS 800    // head scratch overlays PP/OO tail (64 x 25)
#define LDSW  3296

__device__ __forceinline__ u32 pkbf(float a, float b) {
    bfx2 t; t[0] = (__bf16)a; t[1] = (__bf16)b;
    return __builtin_bit_cast(u32, t);
}
__device__ __forceinline__ s16x8 mk8(u32 a, u32 b, u32 c, u32 d) {
    uint4 u; u.x = a; u.y = b; u.z = c; u.w = d;
    return __builtin_bit_cast(s16x8, u);
}
__device__ __forceinline__ void ln6(const float* r, const float* g, const float* bb, float* outv) {
    float m = (r[0]+r[1]+r[2]+r[3]+r[4]+r[5]) * (1.0f/6.0f);
    float v = 0.f;
#pragma unroll
    for (int d = 0; d < DM; ++d) { float t = r[d]-m; v += t*t; }
    v *= (1.0f/6.0f);
    float rs = __builtin_amdgcn_rsqf(v + LNEPS);
#pragma unroll
    for (int d = 0; d < DM; ++d) outv[d] = (r[d]-m)*rs*g[d] + bb[d];
}

__global__ __launch_bounds__(64, 2) void tfenc_kernel(
    const float* __restrict__ input, const float* __restrict__ pos_emb,
    const float* __restrict__ ipw, const float* __restrict__ ipb,
    const float* __restrict__ ow,  const float* __restrict__ obp,
    const float* __restrict__ l1g, const float* __restrict__ l1b,
    const float* __restrict__ f1w, const float* __restrict__ f1b,
    const float* __restrict__ f2w, const float* __restrict__ f2b,
    const float* __restrict__ l2g, const float* __restrict__ l2b,
    const float* __restrict__ hw,  const float* __restrict__ hb,
    float* __restrict__ out)
{
    __shared__ __align__(16) float lds[LDSW];
    __bf16* ldsh = (__bf16*)lds;
    u32*    ldsu = (u32*)lds;

    const int L = threadIdx.x;
    const int b = blockIdx.x;

    // persistent Vt rows: row 7 = zeros (pad d), row 6 = ones (denominator col)
    lds[VT + 700 + L] = 0.f;
    if (L < 36) lds[VT + 700 + 64 + L] = 0.f;
    {
        __bf16 one = (__bf16)1.0f;
        ldsh[6*200 + L] = one;
        ldsh[6*200 + 64 + L] = one;
        ldsh[6*200 + 128 + L] = one;
    }

    float hv[3][DM], xv[3][DM];
#pragma unroll
    for (int i = 0; i < 3; ++i) {
        int r = L + 64*i;
        bool real = (r < LAG);
        xv[i][0] = real ? input[(size_t)b*LAG + r] : 0.f;
#pragma unroll
        for (int j = 0; j < 5; ++j)
            xv[i][1+j] = real ? pos_emb[r*5 + j] : 0.f;
#pragma unroll
        for (int d = 0; d < DM; ++d) hv[i][d] = xv[i][d];
    }

    const float cQ = 0.5889116917845058f;  // log2(e)/sqrt(6)
    const u32 himask = (L & 32) ? 0u : ~0u;
    const int permA = 4*(L & 31);
    const int permB = permA + 128;

#pragma unroll 1
    for (int il = 0; il < NL; ++il) {
        const float* Wip = ipw + il*3*DM*DM;
        const float* bip = ipb + il*3*DM;
        const float* Wo  = ow  + il*DM*DM;
        const float* bo  = obp + il*DM;
        const float* g1  = l1g + il*DM;    const float* c1 = l1b + il*DM;
        const float* W1  = f1w + il*FFD*DM; const float* bb1 = f1b + il*FFD;
        const float* W2  = f2w + il*DM*FFD; const float* bb2 = f2b + il*DM;
        const float* g2  = l2g + il*DM;    const float* c2 = l2b + il*DM;

        // ---- QKV projection; stage V^T to LDS; pack q*cQ, k to bf16 words ----
        u32 qp[3][3], kp[3][3];
#pragma unroll
        for (int i = 0; i < 3; ++i) {
            int r = L + 64*i;
            float qv[6], kv[6], vv[6];
#pragma unroll
            for (int e = 0; e < 18; ++e) {
                float a = bip[e];
#pragma unroll
                for (int d = 0; d < DM; ++d) a += hv[i][d]*Wip[e*DM+d];
                if (e < 6) qv[e] = a*cQ;
                else if (e < 12) kv[e-6] = a;
                else vv[e-12] = a;
            }
            qp[i][0]=pkbf(qv[0],qv[1]); qp[i][1]=pkbf(qv[2],qv[3]); qp[i][2]=pkbf(qv[4],qv[5]);
            kp[i][0]=pkbf(kv[0],kv[1]); kp[i][1]=pkbf(kv[2],kv[3]); kp[i][2]=pkbf(kv[4],kv[5]);
#pragma unroll
            for (int d = 0; d < DM; ++d)
                ldsh[d*200 + r] = (__bf16)vv[d];
        }

        // ---- K fragments (A of 32x32x16): built in-register via bpermute ----
        s16x8 kf[6];
#pragma unroll
        for (int kt = 0; kt < 6; ++kt) {
            int adr = (kt & 1) ? permB : permA;
            int sl = kt >> 1;
            u32 w0 = ((u32)__builtin_amdgcn_ds_bpermute(adr, (int)kp[sl][0])) & himask;
            u32 w1 = ((u32)__builtin_amdgcn_ds_bpermute(adr, (int)kp[sl][1])) & himask;
            u32 w2 = ((u32)__builtin_amdgcn_ds_bpermute(adr, (int)kp[sl][2])) & himask;
            kf[kt] = mk8(w0, w1, w2, 0u);
        }
        // ---- V fragments (B of 16x16x32), cached for the whole layer ----
        s16x8 vf[6];
        {
            int d = L & 15;
            int vrow = d < 7 ? d : 7;
            const u32* vb = ldsu + (VT + vrow*100 + (L >> 4)*4);
#pragma unroll
            for (int kc = 0; kc < 6; ++kc)
                vf[kc] = __builtin_bit_cast(s16x8, *(const uint4*)(vb + kc*16));
        }

        const int wrbase = PP + (L & 31)*18 + 2*(L >> 5);
        const int rdbase = PP + (L & 15)*18 + 4*(L >> 4);

        // ---- attention main loop: S^T = K*Q^T (32x32), exp2, repack, P*V ----
#pragma unroll
        for (int qt = 0; qt < 6; ++qt) {
            int adr = (qt & 1) ? permB : permA;
            int sl = qt >> 1;
            u32 u0 = ((u32)__builtin_amdgcn_ds_bpermute(adr, (int)qp[sl][0])) & himask;
            u32 u1 = ((u32)__builtin_amdgcn_ds_bpermute(adr, (int)qp[sl][1])) & himask;
            u32 u2 = ((u32)__builtin_amdgcn_ds_bpermute(adr, (int)qp[sl][2])) & himask;
            s16x8 qf = mk8(u0, u1, u2, 0u);
            f32x4 acc0 = {0.f,0.f,0.f,0.f};
            f32x4 acc1 = {0.f,0.f,0.f,0.f};
#pragma unroll
            for (int kt = 0; kt < 6; ++kt) {
                f32x16 z = {};
                f32x16 S = __builtin_amdgcn_mfma_f32_32x32x16_bf16(kf[kt], qf, z, 0, 0, 0);
                u32 w[8];
#pragma unroll
                for (int jj = 0; jj < 8; ++jj) {
                    float pa, pb;
                    if (kt == 5 && jj >= 2) { pa = 0.f; pb = 0.f; }  // keys >= 168 masked
                    else {
                        pa = __builtin_amdgcn_exp2f(S[2*jj]);
                        pb = __builtin_amdgcn_exp2f(S[2*jj+1]);
                    }
                    w[jj] = pkbf(pa, pb);
                }
                u32* ppw = ldsu + wrbase + (kt & 1)*576;
                { uint2 t; t.x=w[0]; t.y=w[1]; *(uint2*)(ppw     ) = t; }
                { uint2 t; t.x=w[2]; t.y=w[3]; *(uint2*)(ppw +  4) = t; }
                { uint2 t; t.x=w[4]; t.y=w[5]; *(uint2*)(ppw +  8) = t; }
                { uint2 t; t.x=w[6]; t.y=w[7]; *(uint2*)(ppw + 12) = t; }
                const u32* rr = ldsu + rdbase + (kt & 1)*576;
                uint2 a00 = *(const uint2*)(rr);
                uint2 a01 = *(const uint2*)(rr + 2);
                uint2 a10 = *(const uint2*)(rr + 288);
                uint2 a11 = *(const uint2*)(rr + 290);
                acc0 = __builtin_amdgcn_mfma_f32_16x16x32_bf16(mk8(a00.x,a00.y,a01.x,a01.y), vf[kt], acc0, 0,0,0);
                acc1 = __builtin_amdgcn_mfma_f32_16x16x32_bf16(mk8(a10.x,a10.y,a11.x,a11.y), vf[kt], acc1, 0,0,0);
            }
            // stage O tiles (col d = L&15 < 7 useful; col 6 = softmax denom)
            int d = L & 15;
            if (d < 7) {
                int qb = 32*qt + 4*(L >> 4);
#pragma unroll
                for (int r2 = 0; r2 < 4; ++r2) {
                    lds[OO + (qb + r2)*7 + d]      = acc0[r2];
                    lds[OO + (qb + 16 + r2)*7 + d] = acc1[r2];
                }
            }
        }

        // ---- epilogue per owned row: normalize, out-proj, LN, FF, LN ----
#pragma unroll
        for (int i = 0; i < 3; ++i) {
            int r = L + 64*i;
            float o[7];
#pragma unroll
            for (int d = 0; d < 7; ++d) o[d] = lds[OO + r*7 + d];
            float inv = __builtin_amdgcn_rcpf(o[6]);
            float att[6], rv[6];
#pragma unroll
            for (int d = 0; d < 6; ++d) att[d] = o[d]*inv;
#pragma unroll
            for (int e = 0; e < 6; ++e) {
                float a = bo[e];
#pragma unroll
                for (int d = 0; d < 6; ++d) a += att[d]*Wo[e*6+d];
                rv[e] = hv[i][e] + a;
            }
            ln6(rv, g1, c1, hv[i]);
            float o2[6];
#pragma unroll
            for (int d = 0; d < 6; ++d) o2[d] = bb2[d];
#pragma unroll
            for (int ff = 0; ff < FFD; ++ff) {
                float a = bb1[ff];
#pragma unroll
                for (int d = 0; d < 6; ++d) a += hv[i][d]*W1[ff*6+d];
                a = fmaxf(a, 0.f);
#pragma unroll
                for (int d = 0; d < 6; ++d) o2[d] += a*W2[d*FFD+ff];
            }
#pragma unroll
            for (int d = 0; d < 6; ++d) rv[d] = hv[i][d] + o2[d];
            ln6(rv, g2, c2, hv[i]);
        }
    }

    // ---- final residual+relu (registers), head GEMV ----
    float hf[3][6];
#pragma unroll
    for (int i = 0; i < 3; ++i) {
        int r = L + 64*i;
        bool real = (r < LAG);
#pragma unroll
        for (int d = 0; d < 6; ++d)
            hf[i][d] = real ? fmaxf(hv[i][d] + xv[i][d], 0.f) : 0.f;
    }
    float pt[24];
#pragma unroll
    for (int t = 0; t < 24; ++t) pt[t] = 0.f;
#pragma unroll
    for (int i = 0; i < 3; ++i) {
        int r = L + 64*i;
        if (r < LAG) {
            const float* wr = hw + r*6;
#pragma unroll
            for (int t = 0; t < 24; ++t) {
                const float2* wp = (const float2*)(wr + t*1008);
                float2 w0 = wp[0], w1 = wp[1], w2 = wp[2];
                pt[t] += w0.x*hf[i][0] + w0.y*hf[i][1] + w1.x*hf[i][2]
                       + w1.y*hf[i][3] + w2.x*hf[i][4] + w2.y*hf[i][5];
            }
        }
    }
#pragma unroll
    for (int t = 0; t < 24; ++t) lds[HEADS + L*25 + t] = pt[t];
    if (L < HOR) {
        float s = hb[L];
#pragma unroll 8
        for (int j = 0; j < 64; ++j) s += lds[HEADS + j*25 + L];
        out[(size_t)b*HOR + L] = s;
    }
}

extern "C" void kernel_launch(void* const* d_in, const int* in_sizes, int n_in,
                              void* d_out, int out_size, void* d_ws, size_t ws_size,
                              hipStream_t stream) {
    const float* input   = (const float*)d_in[0];
    const float* pos_emb = (const float*)d_in[1];
    const float* ipw     = (const float*)d_in[2];
    const float* ipb     = (const float*)d_in[3];
    const float* ow      = (const float*)d_in[4];
    const float* ob      = (const float*)d_in[5];
    const float* l1g     = (const float*)d_in[6];
    const float* l1b     = (const float*)d_in[7];
    const float* f1w     = (const float*)d_in[8];
    const float* f1b     = (const float*)d_in[9];
    const float* f2w     = (const float*)d_in[10];
    const float* f2b     = (const float*)d_in[11];
    const float* l2g     = (const float*)d_in[12];
    const float* l2b     = (const float*)d_in[13];
    const float* hw      = (const float*)d_in[14];
    const float* hb      = (const float*)d_in[15];
    float* out = (float*)d_out;

    const int B = in_sizes[0] / LAG;
    tfenc_kernel<<<dim3(B), dim3(64), 0, stream>>>(
        input, pos_emb, ipw, ipb, ow, ob, l1g, l1b,
        f1w, f1b, f2w, f2b, l2g, l2b, hw, hb, out);
}

// Round 3
// 172.264 us; speedup vs baseline: 2.5742x; 1.0805x over previous
//
#include <hip/hip_runtime.h>
#include <math.h>

#define LAG 168
#define HOR 24
#define DM 6
#define FFD 18
#define NL 3
#define LNEPS 1e-5f

typedef unsigned int u32;
typedef float f32x4 __attribute__((ext_vector_type(4)));
typedef float f32x16 __attribute__((ext_vector_type(16)));
typedef short s16x8 __attribute__((ext_vector_type(8)));
typedef __bf16 bfx2 __attribute__((ext_vector_type(2)));

// LDS layout (in 4-byte words) -- single wave per block, all reuse is
// same-wave in-order, so no barriers and no double buffering needed.
#define VT    0      // V^T: 8 rows x 100 words (bf16 [8][200]); row6=ones, row7=zeros
#define PP    800    // P-pack: 576 words (32 q x 18 pitch), single buffer
#define OOH   2752   // O tile in bf16 halves: [192][8], half-index base (=word 1376)
#define HEADS 0      // head scratch overlays VT/PP (used only after layers)
#define LDSW  2144   // 8576 B -> 19 blocks/CU

__device__ __forceinline__ u32 pkbf(float a, float b) {
    bfx2 t; t[0] = (__bf16)a; t[1] = (__bf16)b;
    return __builtin_bit_cast(u32, t);
}
__device__ __forceinline__ s16x8 mk8(u32 a, u32 b, u32 c, u32 d) {
    uint4 u; u.x = a; u.y = b; u.z = c; u.w = d;
    return __builtin_bit_cast(s16x8, u);
}
__device__ __forceinline__ float b2f(unsigned short h) {
    u32 u = ((u32)h) << 16; return __builtin_bit_cast(float, u);
}
__device__ __forceinline__ void ln6(const float* r, const float* g, const float* bb, float* outv) {
    float m = (r[0]+r[1]+r[2]+r[3]+r[4]+r[5]) * (1.0f/6.0f);
    float v = 0.f;
#pragma unroll
    for (int d = 0; d < DM; ++d) { float t = r[d]-m; v += t*t; }
    v *= (1.0f/6.0f);
    float rs = __builtin_amdgcn_rsqf(v + LNEPS);
#pragma unroll
    for (int d = 0; d < DM; ++d) outv[d] = (r[d]-m)*rs*g[d] + bb[d];
}

__global__ __launch_bounds__(64, 4) void tfenc_kernel(
    const float* __restrict__ input, const float* __restrict__ pos_emb,
    const float* __restrict__ ipw, const float* __restrict__ ipb,
    const float* __restrict__ ow,  const float* __restrict__ obp,
    const float* __restrict__ l1g, const float* __restrict__ l1b,
    const float* __restrict__ f1w, const float* __restrict__ f1b,
    const float* __restrict__ f2w, const float* __restrict__ f2b,
    const float* __restrict__ l2g, const float* __restrict__ l2b,
    const float* __restrict__ hw,  const float* __restrict__ hb,
    float* __restrict__ out)
{
    __shared__ __align__(16) float lds[LDSW];
    __bf16* ldsh = (__bf16*)lds;
    u32*    ldsu = (u32*)lds;

    const int L = threadIdx.x;
    const int b = blockIdx.x;

    // persistent Vt rows: row 7 = zeros (pad d), row 6 = ones (denominator col)
    lds[VT + 700 + L] = 0.f;
    if (L < 36) lds[VT + 700 + 64 + L] = 0.f;
    {
        __bf16 one = (__bf16)1.0f;
        ldsh[6*200 + L] = one;
        ldsh[6*200 + 64 + L] = one;
        ldsh[6*200 + 128 + L] = one;
    }

    float hv[3][DM], xv[3][DM];
#pragma unroll
    for (int i = 0; i < 3; ++i) {
        int r = L + 64*i;
        bool real = (r < LAG);
        xv[i][0] = real ? input[(size_t)b*LAG + r] : 0.f;
#pragma unroll
        for (int j = 0; j < 5; ++j)
            xv[i][1+j] = real ? pos_emb[r*5 + j] : 0.f;
#pragma unroll
        for (int d = 0; d < DM; ++d) hv[i][d] = xv[i][d];
    }

    const float cQ = 0.5889116917845058f;  // log2(e)/sqrt(6)
    const u32 himask = (L & 32) ? 0u : ~0u;
    const int permA = 4*(L & 31);
    const int permB = permA + 128;

#pragma unroll 1
    for (int il = 0; il < NL; ++il) {
        const float* Wip = ipw + il*3*DM*DM;
        const float* bip = ipb + il*3*DM;
        const float* Wo  = ow  + il*DM*DM;
        const float* bo  = obp + il*DM;
        const float* g1  = l1g + il*DM;    const float* c1 = l1b + il*DM;
        const float* W1  = f1w + il*FFD*DM; const float* bb1 = f1b + il*FFD;
        const float* W2  = f2w + il*DM*FFD; const float* bb2 = f2b + il*DM;
        const float* g2  = l2g + il*DM;    const float* c2 = l2b + il*DM;

        // ---- QKV projection; stage V^T to LDS; pack q*cQ, k to bf16 words ----
        u32 qp[3][3], kp[3][3];
#pragma unroll
        for (int i = 0; i < 3; ++i) {
            int r = L + 64*i;
            float qv[6], kv[6], vv[6];
#pragma unroll
            for (int e = 0; e < 18; ++e) {
                float a = bip[e];
#pragma unroll
                for (int d = 0; d < DM; ++d) a += hv[i][d]*Wip[e*DM+d];
                if (e < 6) qv[e] = a*cQ;
                else if (e < 12) kv[e-6] = a;
                else vv[e-12] = a;
            }
            qp[i][0]=pkbf(qv[0],qv[1]); qp[i][1]=pkbf(qv[2],qv[3]); qp[i][2]=pkbf(qv[4],qv[5]);
            kp[i][0]=pkbf(kv[0],kv[1]); kp[i][1]=pkbf(kv[2],kv[3]); kp[i][2]=pkbf(kv[4],kv[5]);
#pragma unroll
            for (int d = 0; d < DM; ++d)
                ldsh[d*200 + r] = (__bf16)vv[d];
        }

        // ---- K fragments (A of 32x32x16): built in-register via bpermute ----
        s16x8 kf[6];
#pragma unroll
        for (int kt = 0; kt < 6; ++kt) {
            int adr = (kt & 1) ? permB : permA;
            int sl = kt >> 1;
            u32 w0 = ((u32)__builtin_amdgcn_ds_bpermute(adr, (int)kp[sl][0])) & himask;
            u32 w1 = ((u32)__builtin_amdgcn_ds_bpermute(adr, (int)kp[sl][1])) & himask;
            u32 w2 = ((u32)__builtin_amdgcn_ds_bpermute(adr, (int)kp[sl][2])) & himask;
            kf[kt] = mk8(w0, w1, w2, 0u);
        }
        // ---- V fragments (B of 16x16x32), cached for the whole layer ----
        s16x8 vf[6];
        {
            int d = L & 15;
            int vrow = d < 7 ? d : 7;
            const u32* vb = ldsu + (VT + vrow*100 + (L >> 4)*4);
#pragma unroll
            for (int kc = 0; kc < 6; ++kc)
                vf[kc] = __builtin_bit_cast(s16x8, *(const uint4*)(vb + kc*16));
        }

        const int wrbase = PP + (L & 31)*18 + 2*(L >> 5);
        const int rdbase = PP + (L & 15)*18 + 4*(L >> 4);

        // ---- attention main loop: S^T = K*Q^T (32x32), exp2, repack, P*V ----
#pragma unroll
        for (int qt = 0; qt < 6; ++qt) {
            int adr = (qt & 1) ? permB : permA;
            int sl = qt >> 1;
            u32 u0 = ((u32)__builtin_amdgcn_ds_bpermute(adr, (int)qp[sl][0])) & himask;
            u32 u1 = ((u32)__builtin_amdgcn_ds_bpermute(adr, (int)qp[sl][1])) & himask;
            u32 u2 = ((u32)__builtin_amdgcn_ds_bpermute(adr, (int)qp[sl][2])) & himask;
            s16x8 qf = mk8(u0, u1, u2, 0u);
            f32x4 acc0 = {0.f,0.f,0.f,0.f};
            f32x4 acc1 = {0.f,0.f,0.f,0.f};
#pragma unroll
            for (int kt = 0; kt < 6; ++kt) {
                f32x16 z = {};
                f32x16 S = __builtin_amdgcn_mfma_f32_32x32x16_bf16(kf[kt], qf, z, 0, 0, 0);
                u32 w[8];
#pragma unroll
                for (int jj = 0; jj < 8; ++jj) {
                    float pa, pb;
                    if (kt == 5 && jj >= 2) { pa = 0.f; pb = 0.f; }  // keys >= 168 masked
                    else {
                        pa = __builtin_amdgcn_exp2f(S[2*jj]);
                        pb = __builtin_amdgcn_exp2f(S[2*jj+1]);
                    }
                    w[jj] = pkbf(pa, pb);
                }
                u32* ppw = ldsu + wrbase;
                { uint2 t; t.x=w[0]; t.y=w[1]; *(uint2*)(ppw     ) = t; }
                { uint2 t; t.x=w[2]; t.y=w[3]; *(uint2*)(ppw +  4) = t; }
                { uint2 t; t.x=w[4]; t.y=w[5]; *(uint2*)(ppw +  8) = t; }
                { uint2 t; t.x=w[6]; t.y=w[7]; *(uint2*)(ppw + 12) = t; }
                const u32* rr = ldsu + rdbase;
                uint2 a00 = *(const uint2*)(rr);
                uint2 a01 = *(const uint2*)(rr + 2);
                uint2 a10 = *(const uint2*)(rr + 288);
                uint2 a11 = *(const uint2*)(rr + 290);
                acc0 = __builtin_amdgcn_mfma_f32_16x16x32_bf16(mk8(a00.x,a00.y,a01.x,a01.y), vf[kt], acc0, 0,0,0);
                acc1 = __builtin_amdgcn_mfma_f32_16x16x32_bf16(mk8(a10.x,a10.y,a11.x,a11.y), vf[kt], acc1, 0,0,0);
            }
            // stage O tiles to bf16 (col d = L&15 < 7 useful; col 6 = denom)
            int d = L & 15;
            if (d < 7) {
                int qb = 32*qt + 4*(L >> 4);
                __bf16* ob16 = ldsh + OOH;
#pragma unroll
                for (int r2 = 0; r2 < 4; ++r2) {
                    ob16[(qb + r2)*8 + d]      = (__bf16)acc0[r2];
                    ob16[(qb + 16 + r2)*8 + d] = (__bf16)acc1[r2];
                }
            }
        }

        // ---- epilogue per owned row: normalize, out-proj, LN, FF, LN ----
#pragma unroll
        for (int i = 0; i < 3; ++i) {
            int r = L + 64*i;
            s16x8 ov = __builtin_bit_cast(s16x8, *(const uint4*)(ldsh + OOH + r*8));
            float o[7];
#pragma unroll
            for (int d = 0; d < 7; ++d) o[d] = b2f((unsigned short)ov[d]);
            float inv = __builtin_amdgcn_rcpf(o[6]);
            float att[6], rv[6];
#pragma unroll
            for (int d = 0; d < 6; ++d) att[d] = o[d]*inv;
#pragma unroll
            for (int e = 0; e < 6; ++e) {
                float a = bo[e];
#pragma unroll
                for (int d = 0; d < 6; ++d) a += att[d]*Wo[e*6+d];
                rv[e] = hv[i][e] + a;
            }
            ln6(rv, g1, c1, hv[i]);
            float o2[6];
#pragma unroll
            for (int d = 0; d < 6; ++d) o2[d] = bb2[d];
#pragma unroll
            for (int ff = 0; ff < FFD; ++ff) {
                float a = bb1[ff];
#pragma unroll
                for (int d = 0; d < 6; ++d) a += hv[i][d]*W1[ff*6+d];
                a = fmaxf(a, 0.f);
#pragma unroll
                for (int d = 0; d < 6; ++d) o2[d] += a*W2[d*FFD+ff];
            }
#pragma unroll
            for (int d = 0; d < 6; ++d) rv[d] = hv[i][d] + o2[d];
            ln6(rv, g2, c2, hv[i]);
        }
    }

    // ---- final residual+relu (registers), head GEMV ----
    float hf[3][6];
#pragma unroll
    for (int i = 0; i < 3; ++i) {
        int r = L + 64*i;
        bool real = (r < LAG);
#pragma unroll
        for (int d = 0; d < 6; ++d)
            hf[i][d] = real ? fmaxf(hv[i][d] + xv[i][d], 0.f) : 0.f;
    }
    float pt[24];
#pragma unroll
    for (int t = 0; t < 24; ++t) pt[t] = 0.f;
#pragma unroll
    for (int i = 0; i < 3; ++i) {
        int r = L + 64*i;
        if (r < LAG) {
            const float* wr = hw + r*6;
#pragma unroll
            for (int t = 0; t < 24; ++t) {
                const float2* wp = (const float2*)(wr + t*1008);
                float2 w0 = wp[0], w1 = wp[1], w2 = wp[2];
                pt[t] += w0.x*hf[i][0] + w0.y*hf[i][1] + w1.x*hf[i][2]
                       + w1.y*hf[i][3] + w2.x*hf[i][4] + w2.y*hf[i][5];
            }
        }
    }
#pragma unroll
    for (int t = 0; t < 24; ++t) lds[HEADS + L*25 + t] = pt[t];
    if (L < HOR) {
        float s = hb[L];
#pragma unroll 8
        for (int j = 0; j < 64; ++j) s += lds[HEADS + j*25 + L];
        out[(size_t)b*HOR + L] = s;
    }
}

extern "C" void kernel_launch(void* const* d_in, const int* in_sizes, int n_in,
                              void* d_out, int out_size, void* d_ws, size_t ws_size,
                              hipStream_t stream) {
    const float* input   = (const float*)d_in[0];
    const float* pos_emb = (const float*)d_in[1];
    const float* ipw     = (const float*)d_in[2];
    const float* ipb     = (const float*)d_in[3];
    const float* ow      = (const float*)d_in[4];
    const float* ob      = (const float*)d_in[5];
    const float* l1g     = (const float*)d_in[6];
    const float* l1b     = (const float*)d_in[7];
    const float* f1w     = (const float*)d_in[8];
    const float* f1b     = (const float*)d_in[9];
    const float* f2w     = (const float*)d_in[10];
    const float* f2b     = (const float*)d_in[11];
    const float* l2g     = (const float*)d_in[12];
    const float* l2b     = (const float*)d_in[13];
    const float* hw      = (const float*)d_in[14];
    const float* hb      = (const float*)d_in[15];
    float* out = (float*)d_out;

    const int B = in_sizes[0] / LAG;
    tfenc_kernel<<<dim3(B), dim3(64), 0, stream>>>(
        input, pos_emb, ipw, ipb, ow, ob, l1g, l1b,
        f1w, f1b, f2w, f2b, l2g, l2b, hw, hb, out);
}